// Round 10
// baseline (272.091 us; speedup 1.0000x reference)
//
#include <hip/hip_runtime.h>
#include <hip/hip_bf16.h>
#include <stdint.h>

#define BB 4
#define SS 2048
#define DD 512
#define HH 512

typedef __attribute__((ext_vector_type(8))) short short8;
typedef __attribute__((ext_vector_type(4))) float floatx4;

typedef __attribute__((address_space(3))) uint32_t lds_u32_t;
typedef const __attribute__((address_space(1))) uint32_t glb_u32_t;

__device__ __forceinline__ void gload_lds16(const void* g, void* l) {
  __builtin_amdgcn_global_load_lds((glb_u32_t*)g, (lds_u32_t*)l, 16, 0, 0);
}

__device__ __forceinline__ short f2bf(float f) {
  __hip_bfloat16 h = __float2bfloat16(f);
  return __builtin_bit_cast(short, h);
}

__device__ __forceinline__ float bf2f(short s) {
  uint32_t u = ((uint32_t)(uint16_t)s) << 16;
  return __builtin_bit_cast(float, u);
}

// ---------------- GEMM main loop: acc += A-tile * B-tile^T ----------------
// A: [M,K] bf16 (lda), B: [N,K] bf16 (ldb). 4 waves in 2x2 grid, BN=128.
// BK=64, single-buffered (r5 config — dbuf regressed, r9). LDS rows are
// 8 x 16B chunks; chunk c of row r holds global chunk c ^ (r&7)
// (source-side pre-swizzle; ds_read applies the same XOR).
template <int BM>
__device__ __forceinline__ void gemm_mainloop(const short* __restrict__ Ab,
                                              const short* __restrict__ Bb,
                                              int lda, int ldb, int K,
                                              floatx4 (&acc)[BM / 32][4]) {
  constexpr int BK = 64;
  constexpr int MF = BM / 32;
  __shared__ short As[BM * BK];
  __shared__ short Bs[128 * BK];

  const int t = threadIdx.x;
  const int lane = t & 63;
  const int wid = t >> 6;
  const int wr = wid >> 1, wc = wid & 1;
  const int r16 = lane & 15;
  const int hi = lane >> 4;  // 0..3

  const int srow = t >> 3;   // staging row within a 32-row slab
  const int schunk = t & 7;  // LDS 16B slot index within the row

#pragma unroll
  for (int i = 0; i < MF; i++)
#pragma unroll
    for (int j = 0; j < 4; j++) acc[i][j] = (floatx4)0.f;

  for (int k0 = 0; k0 < K; k0 += BK) {
#pragma unroll
    for (int s = 0; s < BM / 32; s++) {
      const int row = s * 32 + srow;
      const int g = schunk ^ (row & 7);  // global chunk for this LDS slot
      gload_lds16(Ab + (long)row * lda + k0 + g * 8,
                  &As[row * BK + schunk * 8]);
    }
#pragma unroll
    for (int s = 0; s < 4; s++) {
      const int row = s * 32 + srow;
      const int g = schunk ^ (row & 7);
      gload_lds16(Bb + (long)row * ldb + k0 + g * 8,
                  &Bs[row * BK + schunk * 8]);
    }
    __syncthreads();

    short8 af[MF][2], bfr[4][2];
#pragma unroll
    for (int i = 0; i < MF; i++) {
      const int row = wr * (BM / 2) + i * 16 + r16;
      const int x7 = row & 7;
      af[i][0] = *(const short8*)&As[row * BK + (hi ^ x7) * 8];
      af[i][1] = *(const short8*)&As[row * BK + ((hi + 4) ^ x7) * 8];
    }
#pragma unroll
    for (int j = 0; j < 4; j++) {
      const int row = wc * 64 + j * 16 + r16;
      const int x7 = row & 7;
      bfr[j][0] = *(const short8*)&Bs[row * BK + (hi ^ x7) * 8];
      bfr[j][1] = *(const short8*)&Bs[row * BK + ((hi + 4) ^ x7) * 8];
    }
#pragma unroll
    for (int i = 0; i < MF; i++)
#pragma unroll
      for (int j = 0; j < 4; j++) {
        acc[i][j] = __builtin_amdgcn_mfma_f32_16x16x32_bf16(
            af[i][0], bfr[j][0], acc[i][j], 0, 0, 0);
        acc[i][j] = __builtin_amdgcn_mfma_f32_16x16x32_bf16(
            af[i][1], bfr[j][1], acc[i][j], 0, 0, 0);
      }
    __syncthreads();
  }
}

// Standard row-major epilogue. C/D layout: col = lane&15, row = (lane>>4)*4+reg.
// EPI: 0 plain->bf16, 2 sigmoid(v+bias)->bf16, 3 plain->f32
template <int BM, int EPI>
__device__ __forceinline__ void epilogue_std(floatx4 (&acc)[BM / 32][4],
                                             void* __restrict__ Cm, long c_base,
                                             const float* __restrict__ bias,
                                             int ldc, long row0, long col0) {
  const int lane = threadIdx.x & 63;
  const int wid = threadIdx.x >> 6;
  const int wr = wid >> 1, wc = wid & 1;
  const int r16 = lane & 15;
#pragma unroll
  for (int i = 0; i < BM / 32; i++) {
    const long rbase = row0 + wr * (BM / 2) + i * 16 + (lane >> 4) * 4;
#pragma unroll
    for (int j = 0; j < 4; j++) {
      const long col = col0 + wc * 64 + j * 16 + r16;
      float bv = 0.f;
      if (EPI == 2) bv = bias[col];
#pragma unroll
      for (int rg = 0; rg < 4; rg++) {
        float v = acc[i][j][rg];
        if (EPI == 2) v = 1.f / (1.f + __expf(-(v + bv)));
        const long idx = c_base + (rbase + rg) * ldc + col;
        if (EPI == 3)
          ((float*)Cm)[idx] = v;
        else
          ((__hip_bfloat16*)Cm)[idx] = __float2bfloat16(v);
      }
    }
  }
}

template <int BM, int EPI>
__global__ __launch_bounds__(256) void gemm_bt(
    const short* __restrict__ A, const short* __restrict__ Bm,
    void* __restrict__ Cm, const float* __restrict__ bias, int K, int lda,
    int ldb, int ldc, long sA, long sB, long sC) {
  const int bz = blockIdx.z;
  floatx4 acc[BM / 32][4];
  const long row0 = (long)blockIdx.x * BM, col0 = (long)blockIdx.y * 128;
  gemm_mainloop<BM>(A + bz * sA + row0 * lda, Bm + bz * sB + col0 * ldb, lda,
                    ldb, K, acc);
  epilogue_std<BM, EPI>(acc, Cm, bz * sC, bias, ldc, row0, col0);
}

// Stage 1: qkv projection with direct-layout outputs. BM=128.
// y 0..3 -> q [b][S][H] row-major; y 4..7 -> kT [b][H][S]; y 8..11 -> vT.
__global__ __launch_bounds__(256) void gemm_qkv(
    const short* __restrict__ xb, const short* __restrict__ WT,
    const float* __restrict__ bcat, short* __restrict__ q,
    short* __restrict__ kT, short* __restrict__ vT) {
  floatx4 acc[4][4];
  const long row0 = (long)blockIdx.x * 128;  // global row over B*S
  const int y = blockIdx.y;
  gemm_mainloop<128>(xb + row0 * DD, WT + (long)y * 128 * DD, DD, DD, DD, acc);

  const int lane = threadIdx.x & 63;
  const int wid = threadIdx.x >> 6;
  const int wr = wid >> 1, wc = wid & 1;
  const int r16 = lane & 15;
  const int hi4 = (lane >> 4) * 4;
  const int mode = y >> 2;
  const int b = (int)(row0 >> 11);
  const int sblk = (int)(row0 & 2047);
  short* tp = (mode == 1) ? kT : vT;
#pragma unroll
  for (int i = 0; i < 4; i++) {
    const int s0 = sblk + wr * 64 + i * 16 + hi4;
#pragma unroll
    for (int j = 0; j < 4; j++) {
      const int colg = y * 128 + wc * 64 + j * 16 + r16;
      const float bv = bcat[colg];
      short o[4];
#pragma unroll
      for (int rg = 0; rg < 4; rg++) o[rg] = f2bf(acc[i][j][rg] + bv);
      if (mode == 0) {
#pragma unroll
        for (int rg = 0; rg < 4; rg++)
          q[((long)b * SS + s0 + rg) * HH + colg] = o[rg];
      } else {
        const int cl = colg - mode * 512;
        *(uint64_t*)&tp[((long)b * HH + cl) * SS + s0] = *(uint64_t*)o;
      }
    }
  }
}

// Split-K dual GEMM with TAIL-BLOCK reduction. BM=64.
// z = tb*4 + split; tb = task*4 + b.
// task 0: M2[b] = WdT @ kT[b]^T ; task 1: M3t[b] = xT[b] @ vT[b]^T
// Each split writes a bf16 partial; the LAST split-block of a tile
// (device-scope atomic counter, zeroed by prep) sums the 4 partials into
// M2/M3t. Partials are read with agent-scope atomic loads (coherent across
// XCD L2s); writers publish with __threadfence() before the counter bump.
__global__ __launch_bounds__(256) void gemm_dual_split(
    const short* __restrict__ WdT, const short* __restrict__ kT,
    short* __restrict__ partM2, const short* __restrict__ xT,
    const short* __restrict__ vT, short* __restrict__ partM3,
    int* __restrict__ cnt, short* __restrict__ M2, short* __restrict__ M3t) {
  const int bz = blockIdx.z;
  const int tb = bz >> 2, sp = bz & 3;
  const int task = tb >> 2, b = tb & 3;
  const short* A = (task ? xT + (long)b * HH * SS : WdT) + sp * 512;
  const short* B = (task ? vT : kT) + (long)b * HH * SS + sp * 512;
  short* parts = task ? partM3 : partM2;
  short* C = parts + ((long)b * 4 + sp) * HH * HH;
  floatx4 acc[2][4];
  const long row0 = (long)blockIdx.x * 64, col0 = (long)blockIdx.y * 128;
  gemm_mainloop<64>(A + row0 * SS, B + col0 * SS, SS, SS, 512, acc);
  epilogue_std<64, 0>(acc, C, 0, nullptr, HH, row0, col0);

  // ---- tail-block reduction ----
  const int t = threadIdx.x;
  const int tileid = (tb * 8 + blockIdx.x) * 4 + blockIdx.y;
  __shared__ int is_last;
  __threadfence();  // publish this block's partial stores (device scope)
  __syncthreads();
  if (t == 0) is_last = (atomicAdd(&cnt[tileid], 1) == 3);
  __syncthreads();
  if (!is_last) return;
  __threadfence();

  short* dst = (task ? M3t : M2) + (long)b * HH * HH;
  const long row = row0 + (t >> 2);
  const long c0 = col0 + (long)(t & 3) * 32;
#pragma unroll
  for (int ch = 0; ch < 4; ch++) {
    float s[8];
#pragma unroll
    for (int j = 0; j < 8; j++) s[j] = 0.f;
#pragma unroll
    for (int sp2 = 0; sp2 < 4; sp2++) {
      const unsigned long long* p =
          (const unsigned long long*)&parts[((long)b * 4 + sp2) * HH * HH +
                                            row * HH + c0 + ch * 8];
      unsigned long long lo =
          __hip_atomic_load(p, __ATOMIC_RELAXED, __HIP_MEMORY_SCOPE_AGENT);
      unsigned long long hi =
          __hip_atomic_load(p + 1, __ATOMIC_RELAXED, __HIP_MEMORY_SCOPE_AGENT);
#pragma unroll
      for (int j = 0; j < 4; j++) s[j] += bf2f((short)(lo >> (16 * j)));
#pragma unroll
      for (int j = 0; j < 4; j++) s[4 + j] += bf2f((short)(hi >> (16 * j)));
    }
    short o[8];
#pragma unroll
    for (int j = 0; j < 8; j++) o[j] = f2bf(s[j]);
    *(short8*)&dst[row * HH + c0 + ch * 8] = *(short8*)o;
  }
}

// ---------------- fused prep: x conversions + all weight prep ----------------
// grid (16, 64, 8), block (32,8).
// z 0..3: batch z of x: f32 [S][D] -> xb bf16 same layout AND xT bf16 [D][S]
// z 4..6: W{q,k,v} [512][512] -> WT[z-4] transposed bf16 (y<16)
//         z==4, y 16..21, x==0: bcat = [bq|bk|bv]
// z 7:    Wd [2048][512] -> WdT [512][2048] bf16; block (0,0,7) zeroes cnt
__global__ void prep(const float* __restrict__ x, const float* __restrict__ Wq,
                     const float* __restrict__ Wk, const float* __restrict__ Wv,
                     const float* __restrict__ Wd, const float* __restrict__ bq,
                     const float* __restrict__ bk, const float* __restrict__ bv,
                     short* __restrict__ xb, short* __restrict__ xT,
                     short* __restrict__ WT, short* __restrict__ WdT,
                     float* __restrict__ bcat, int* __restrict__ cnt) {
  __shared__ float tile[32][33];
  const int z = blockIdx.z, yb = blockIdx.y;
  const int tx = threadIdx.x, ty = threadIdx.y;
  if (z < 4) {
    const long b = z;
    const float* in = x + b * SS * DD;
    const int c0 = blockIdx.x * 32, r0 = yb * 32;  // c over D, r over S
#pragma unroll
    for (int i = 0; i < 32; i += 8) {
      float v = in[(long)(r0 + ty + i) * DD + c0 + tx];
      tile[ty + i][tx] = v;
      xb[(b * SS + r0 + ty + i) * DD + c0 + tx] = f2bf(v);
    }
    __syncthreads();
#pragma unroll
    for (int i = 0; i < 32; i += 8)
      xT[(b * DD + c0 + ty + i) * SS + r0 + tx] = f2bf(tile[tx][ty + i]);
  } else if (z < 7) {
    const int w = z - 4;
    if (yb < 16) {
      const float* in = w == 0 ? Wq : (w == 1 ? Wk : Wv);
      short* out = WT + (long)w * HH * DD;
      const int c0 = blockIdx.x * 32, r0 = yb * 32;
#pragma unroll
      for (int i = 0; i < 32; i += 8)
        tile[ty + i][tx] = in[(long)(r0 + ty + i) * HH + c0 + tx];
      __syncthreads();
#pragma unroll
      for (int i = 0; i < 32; i += 8)
        out[(long)(c0 + ty + i) * DD + r0 + tx] = f2bf(tile[tx][ty + i]);
    } else if (w == 0 && yb < 22 && blockIdx.x == 0) {
      const int i = (yb - 16) * 256 + ty * 32 + tx;
      bcat[i] = i < 512 ? bq[i] : (i < 1024 ? bk[i - 512] : bv[i - 1024]);
    }
  } else {
    if (yb == 0 && blockIdx.x == 0) cnt[ty * 32 + tx] = 0;  // 256 counters
    const int c0 = blockIdx.x * 32, r0 = yb * 32;  // c over H, r over S
#pragma unroll
    for (int i = 0; i < 32; i += 8)
      tile[ty + i][tx] = Wd[(long)(r0 + ty + i) * HH + c0 + tx];
    __syncthreads();
#pragma unroll
    for (int i = 0; i < 32; i += 8)
      WdT[(long)(c0 + ty + i) * SS + r0 + tx] = f2bf(tile[tx][ty + i]);
  }
}

extern "C" void kernel_launch(void* const* d_in, const int* in_sizes, int n_in,
                              void* d_out, int out_size, void* d_ws,
                              size_t ws_size, hipStream_t stream) {
  (void)in_sizes;
  (void)n_in;
  (void)out_size;
  (void)ws_size;
  const float* x = (const float*)d_in[0];
  const float* Wq = (const float*)d_in[1];
  const float* bq = (const float*)d_in[2];
  const float* Wk = (const float*)d_in[3];
  const float* bk = (const float*)d_in[4];
  const float* Wv = (const float*)d_in[5];
  const float* bv = (const float*)d_in[6];
  const float* Wd = (const float*)d_in[7];
  const float* bd = (const float*)d_in[8];

  char* w = (char*)d_ws;
  auto alloc = [&](size_t bytes) {
    char* p = w;
    w += (bytes + 255) & ~(size_t)255;
    return p;
  };
  short* xb = (short*)alloc((size_t)BB * SS * DD * 2);          // 8MB
  short* xT = (short*)alloc((size_t)BB * DD * SS * 2);          // 8MB
  short* WT = (short*)alloc((size_t)3 * HH * DD * 2);           // 1.5MB
  short* WdT = (short*)alloc((size_t)HH * SS * 2);              // 2MB
  float* bcat = (float*)alloc((size_t)3 * HH * 4);
  int* cnt = (int*)alloc((size_t)256 * 4);                      // 1KB
  short* q = (short*)alloc((size_t)BB * SS * HH * 2);           // 8MB
  short* kT = (short*)alloc((size_t)BB * HH * SS * 2);          // 8MB
  short* vT = (short*)alloc((size_t)BB * HH * SS * 2);          // 8MB
  short* partM2 = (short*)alloc((size_t)BB * 4 * HH * HH * 2);  // 8MB
  short* partM3 = (short*)alloc((size_t)BB * 4 * HH * HH * 2);  // 8MB
  short* M2 = (short*)alloc((size_t)BB * HH * HH * 2);          // 2MB
  short* M3t = (short*)alloc((size_t)BB * DD * HH * 2);         // 2MB
  short* dense = (short*)alloc((size_t)BB * SS * HH * 2);       // 8MB

  dim3 tb(32, 8);
  prep<<<dim3(16, 64, 8), tb, 0, stream>>>(x, Wq, Wk, Wv, Wd, bq, bk, bv, xb,
                                           xT, WT, WdT, bcat, cnt);

  // Stage 1: q/kT/vT = x @ [Wq|Wk|Wv] + bias, direct layouts (768 blocks)
  gemm_qkv<<<dim3(BB * SS / 128, 12, 1), 256, 0, stream>>>(xb, WT, bcat, q, kT,
                                                           vT);
  // Stage 2a+3a split-K + in-kernel tail reduction (1024 blocks)
  gemm_dual_split<<<dim3(8, 4, 32), 256, 0, stream>>>(WdT, kT, partM2, xT, vT,
                                                      partM3, cnt, M2, M3t);
  // Stage 2b: dense = sigmoid(q @ M2^T + bd)   [2048,512] K=512, batch 4
  gemm_bt<64, 2><<<dim3(SS / 64, HH / 128, BB), 256, 0, stream>>>(
      q, M2, dense, bd, HH, HH, HH, HH, (long)SS * HH, (long)HH * HH,
      (long)SS * HH);
  // Stage 3b: out = dense @ M3t^T   [2048,512] K=512, batch 4, f32 out
  gemm_bt<64, 3><<<dim3(SS / 64, DD / 128, BB), 256, 0, stream>>>(
      dense, M3t, d_out, nullptr, HH, HH, HH, DD, (long)SS * HH, (long)DD * HH,
      (long)SS * DD);
}

// Round 11
// 81.785 us; speedup vs baseline: 3.3269x; 3.3269x over previous
//
#include <hip/hip_runtime.h>
#include <hip/hip_bf16.h>
#include <stdint.h>

#define BB 4
#define SS 2048
#define DD 512
#define HH 512

typedef __attribute__((ext_vector_type(8))) short short8;
typedef __attribute__((ext_vector_type(4))) float floatx4;

typedef __attribute__((address_space(3))) uint32_t lds_u32_t;
typedef const __attribute__((address_space(1))) uint32_t glb_u32_t;

__device__ __forceinline__ void gload_lds16(const void* g, void* l) {
  __builtin_amdgcn_global_load_lds((glb_u32_t*)g, (lds_u32_t*)l, 16, 0, 0);
}

__device__ __forceinline__ short f2bf(float f) {
  __hip_bfloat16 h = __float2bfloat16(f);
  return __builtin_bit_cast(short, h);
}

__device__ __forceinline__ float bf2f(short s) {
  uint32_t u = ((uint32_t)(uint16_t)s) << 16;
  return __builtin_bit_cast(float, u);
}

// ---------------- GEMM main loop: acc += A-tile * B-tile^T ----------------
// A: [M,K] bf16 (lda), B: [N,K] bf16 (ldb). 4 waves in 2x2 grid, BN=128.
// BK=64, single-buffered (best measured: r5=81.9us; dbuf r9 and tail-reduce
// r10 both regressed). LDS rows are 8 x 16B chunks; chunk c of row r holds
// global chunk c ^ (r&7) (source-side pre-swizzle; ds_read same XOR).
template <int BM>
__device__ __forceinline__ void gemm_mainloop(const short* __restrict__ Ab,
                                              const short* __restrict__ Bb,
                                              int lda, int ldb, int K,
                                              floatx4 (&acc)[BM / 32][4]) {
  constexpr int BK = 64;
  constexpr int MF = BM / 32;
  __shared__ short As[BM * BK];
  __shared__ short Bs[128 * BK];

  const int t = threadIdx.x;
  const int lane = t & 63;
  const int wid = t >> 6;
  const int wr = wid >> 1, wc = wid & 1;
  const int r16 = lane & 15;
  const int hi = lane >> 4;  // 0..3

  const int srow = t >> 3;   // staging row within a 32-row slab
  const int schunk = t & 7;  // LDS 16B slot index within the row

#pragma unroll
  for (int i = 0; i < MF; i++)
#pragma unroll
    for (int j = 0; j < 4; j++) acc[i][j] = (floatx4)0.f;

  for (int k0 = 0; k0 < K; k0 += BK) {
#pragma unroll
    for (int s = 0; s < BM / 32; s++) {
      const int row = s * 32 + srow;
      const int g = schunk ^ (row & 7);  // global chunk for this LDS slot
      gload_lds16(Ab + (long)row * lda + k0 + g * 8,
                  &As[row * BK + schunk * 8]);
    }
#pragma unroll
    for (int s = 0; s < 4; s++) {
      const int row = s * 32 + srow;
      const int g = schunk ^ (row & 7);
      gload_lds16(Bb + (long)row * ldb + k0 + g * 8,
                  &Bs[row * BK + schunk * 8]);
    }
    __syncthreads();

    short8 af[MF][2], bfr[4][2];
#pragma unroll
    for (int i = 0; i < MF; i++) {
      const int row = wr * (BM / 2) + i * 16 + r16;
      const int x7 = row & 7;
      af[i][0] = *(const short8*)&As[row * BK + (hi ^ x7) * 8];
      af[i][1] = *(const short8*)&As[row * BK + ((hi + 4) ^ x7) * 8];
    }
#pragma unroll
    for (int j = 0; j < 4; j++) {
      const int row = wc * 64 + j * 16 + r16;
      const int x7 = row & 7;
      bfr[j][0] = *(const short8*)&Bs[row * BK + (hi ^ x7) * 8];
      bfr[j][1] = *(const short8*)&Bs[row * BK + ((hi + 4) ^ x7) * 8];
    }
#pragma unroll
    for (int i = 0; i < MF; i++)
#pragma unroll
      for (int j = 0; j < 4; j++) {
        acc[i][j] = __builtin_amdgcn_mfma_f32_16x16x32_bf16(
            af[i][0], bfr[j][0], acc[i][j], 0, 0, 0);
        acc[i][j] = __builtin_amdgcn_mfma_f32_16x16x32_bf16(
            af[i][1], bfr[j][1], acc[i][j], 0, 0, 0);
      }
    __syncthreads();
  }
}

// Standard row-major epilogue. C/D layout: col = lane&15, row = (lane>>4)*4+reg.
// EPI: 0 plain->bf16, 2 sigmoid(v+bias)->bf16, 3 plain->f32
template <int BM, int EPI>
__device__ __forceinline__ void epilogue_std(floatx4 (&acc)[BM / 32][4],
                                             void* __restrict__ Cm, long c_base,
                                             const float* __restrict__ bias,
                                             int ldc, long row0, long col0) {
  const int lane = threadIdx.x & 63;
  const int wid = threadIdx.x >> 6;
  const int wr = wid >> 1, wc = wid & 1;
  const int r16 = lane & 15;
#pragma unroll
  for (int i = 0; i < BM / 32; i++) {
    const long rbase = row0 + wr * (BM / 2) + i * 16 + (lane >> 4) * 4;
#pragma unroll
    for (int j = 0; j < 4; j++) {
      const long col = col0 + wc * 64 + j * 16 + r16;
      float bv = 0.f;
      if (EPI == 2) bv = bias[col];
#pragma unroll
      for (int rg = 0; rg < 4; rg++) {
        float v = acc[i][j][rg];
        if (EPI == 2) v = 1.f / (1.f + __expf(-(v + bv)));
        const long idx = c_base + (rbase + rg) * ldc + col;
        if (EPI == 3)
          ((float*)Cm)[idx] = v;
        else
          ((__hip_bfloat16*)Cm)[idx] = __float2bfloat16(v);
      }
    }
  }
}

template <int BM, int EPI>
__global__ __launch_bounds__(256) void gemm_bt(
    const short* __restrict__ A, const short* __restrict__ Bm,
    void* __restrict__ Cm, const float* __restrict__ bias, int K, int lda,
    int ldb, int ldc, long sA, long sB, long sC) {
  const int bz = blockIdx.z;
  floatx4 acc[BM / 32][4];
  const long row0 = (long)blockIdx.x * BM, col0 = (long)blockIdx.y * 128;
  gemm_mainloop<BM>(A + bz * sA + row0 * lda, Bm + bz * sB + col0 * ldb, lda,
                    ldb, K, acc);
  epilogue_std<BM, EPI>(acc, Cm, bz * sC, bias, ldc, row0, col0);
}

// Stage 1: qkv projection with direct-layout outputs. BM=128.
// y 0..3 -> q [b][S][H] row-major; y 4..7 -> kT [b][H][S]; y 8..11 -> vT.
__global__ __launch_bounds__(256) void gemm_qkv(
    const short* __restrict__ xb, const short* __restrict__ WT,
    const float* __restrict__ bcat, short* __restrict__ q,
    short* __restrict__ kT, short* __restrict__ vT) {
  floatx4 acc[4][4];
  const long row0 = (long)blockIdx.x * 128;  // global row over B*S
  const int y = blockIdx.y;
  gemm_mainloop<128>(xb + row0 * DD, WT + (long)y * 128 * DD, DD, DD, DD, acc);

  const int lane = threadIdx.x & 63;
  const int wid = threadIdx.x >> 6;
  const int wr = wid >> 1, wc = wid & 1;
  const int r16 = lane & 15;
  const int hi4 = (lane >> 4) * 4;
  const int mode = y >> 2;
  const int b = (int)(row0 >> 11);
  const int sblk = (int)(row0 & 2047);
  short* tp = (mode == 1) ? kT : vT;
#pragma unroll
  for (int i = 0; i < 4; i++) {
    const int s0 = sblk + wr * 64 + i * 16 + hi4;
#pragma unroll
    for (int j = 0; j < 4; j++) {
      const int colg = y * 128 + wc * 64 + j * 16 + r16;
      const float bv = bcat[colg];
      short o[4];
#pragma unroll
      for (int rg = 0; rg < 4; rg++) o[rg] = f2bf(acc[i][j][rg] + bv);
      if (mode == 0) {
#pragma unroll
        for (int rg = 0; rg < 4; rg++)
          q[((long)b * SS + s0 + rg) * HH + colg] = o[rg];
      } else {
        const int cl = colg - mode * 512;
        *(uint64_t*)&tp[((long)b * HH + cl) * SS + s0] = *(uint64_t*)o;
      }
    }
  }
}

// Split-K dual GEMM. BM=64. z = tb*4 + split; tb = task*4 + b.
// task 0: M2[b] = WdT @ kT[b]^T ; task 1: M3t[b] = xT[b] @ vT[b]^T
__global__ __launch_bounds__(256) void gemm_dual_split(
    const short* __restrict__ WdT, const short* __restrict__ kT,
    short* __restrict__ partM2, const short* __restrict__ xT,
    const short* __restrict__ vT, short* __restrict__ partM3) {
  const int bz = blockIdx.z;
  const int tb = bz >> 2, sp = bz & 3;
  const int task = tb >> 2, b = tb & 3;
  const short* A = (task ? xT + (long)b * HH * SS : WdT) + sp * 512;
  const short* B = (task ? vT : kT) + (long)b * HH * SS + sp * 512;
  short* C = (task ? partM3 : partM2) + ((long)(tb & 3) * 4 + sp) * HH * HH;
  floatx4 acc[2][4];
  const long row0 = (long)blockIdx.x * 64, col0 = (long)blockIdx.y * 128;
  gemm_mainloop<64>(A + row0 * SS, B + col0 * SS, SS, SS, 512, acc);
  epilogue_std<64, 0>(acc, C, 0, nullptr, HH, row0, col0);
}

// Sum 4 bf16 partials -> bf16. z = 0..7 (task*4+b), 8 elems/thread.
__global__ __launch_bounds__(256) void reduce_part(
    const short* __restrict__ partM2, const short* __restrict__ partM3,
    short* __restrict__ M2, short* __restrict__ M3t) {
  const int z = blockIdx.z;
  const int b = z & 3;
  const short* src = (z < 4 ? partM2 : partM3) + (long)b * 4 * HH * HH;
  short* dst = (z < 4 ? M2 : M3t) + (long)b * HH * HH;
  const long i = ((long)blockIdx.x * 256 + threadIdx.x) * 8;
  float s[8];
#pragma unroll
  for (int j = 0; j < 8; j++) s[j] = 0.f;
#pragma unroll
  for (int sp = 0; sp < 4; sp++) {
    short8 v = *(const short8*)&src[(long)sp * HH * HH + i];
#pragma unroll
    for (int j = 0; j < 8; j++) s[j] += bf2f(v[j]);
  }
  short o[8];
#pragma unroll
  for (int j = 0; j < 8; j++) o[j] = f2bf(s[j]);
  *(short8*)&dst[i] = *(short8*)o;
}

// ---------------- fused prep: x conversions + all weight prep ----------------
// grid (16, 64, 8), block (32,8).
// z 0..3: batch z of x: f32 [S][D] -> xb bf16 same layout AND xT bf16 [D][S]
// z 4..6: W{q,k,v} [512][512] -> WT[z-4] transposed bf16 (y<16)
//         z==4, y 16..21, x==0: bcat = [bq|bk|bv]
// z 7:    Wd [2048][512] -> WdT [512][2048] bf16
__global__ void prep(const float* __restrict__ x, const float* __restrict__ Wq,
                     const float* __restrict__ Wk, const float* __restrict__ Wv,
                     const float* __restrict__ Wd, const float* __restrict__ bq,
                     const float* __restrict__ bk, const float* __restrict__ bv,
                     short* __restrict__ xb, short* __restrict__ xT,
                     short* __restrict__ WT, short* __restrict__ WdT,
                     float* __restrict__ bcat) {
  __shared__ float tile[32][33];
  const int z = blockIdx.z, yb = blockIdx.y;
  const int tx = threadIdx.x, ty = threadIdx.y;
  if (z < 4) {
    const long b = z;
    const float* in = x + b * SS * DD;
    const int c0 = blockIdx.x * 32, r0 = yb * 32;  // c over D, r over S
#pragma unroll
    for (int i = 0; i < 32; i += 8) {
      float v = in[(long)(r0 + ty + i) * DD + c0 + tx];
      tile[ty + i][tx] = v;
      xb[(b * SS + r0 + ty + i) * DD + c0 + tx] = f2bf(v);
    }
    __syncthreads();
#pragma unroll
    for (int i = 0; i < 32; i += 8)
      xT[(b * DD + c0 + ty + i) * SS + r0 + tx] = f2bf(tile[tx][ty + i]);
  } else if (z < 7) {
    const int w = z - 4;
    if (yb < 16) {
      const float* in = w == 0 ? Wq : (w == 1 ? Wk : Wv);
      short* out = WT + (long)w * HH * DD;
      const int c0 = blockIdx.x * 32, r0 = yb * 32;
#pragma unroll
      for (int i = 0; i < 32; i += 8)
        tile[ty + i][tx] = in[(long)(r0 + ty + i) * HH + c0 + tx];
      __syncthreads();
#pragma unroll
      for (int i = 0; i < 32; i += 8)
        out[(long)(c0 + ty + i) * DD + r0 + tx] = f2bf(tile[tx][ty + i]);
    } else if (w == 0 && yb < 22 && blockIdx.x == 0) {
      const int i = (yb - 16) * 256 + ty * 32 + tx;
      bcat[i] = i < 512 ? bq[i] : (i < 1024 ? bk[i - 512] : bv[i - 1024]);
    }
  } else {
    const int c0 = blockIdx.x * 32, r0 = yb * 32;  // c over H, r over S
#pragma unroll
    for (int i = 0; i < 32; i += 8)
      tile[ty + i][tx] = Wd[(long)(r0 + ty + i) * HH + c0 + tx];
    __syncthreads();
#pragma unroll
    for (int i = 0; i < 32; i += 8)
      WdT[(long)(c0 + ty + i) * SS + r0 + tx] = f2bf(tile[tx][ty + i]);
  }
}

extern "C" void kernel_launch(void* const* d_in, const int* in_sizes, int n_in,
                              void* d_out, int out_size, void* d_ws,
                              size_t ws_size, hipStream_t stream) {
  (void)in_sizes;
  (void)n_in;
  (void)out_size;
  (void)ws_size;
  const float* x = (const float*)d_in[0];
  const float* Wq = (const float*)d_in[1];
  const float* bq = (const float*)d_in[2];
  const float* Wk = (const float*)d_in[3];
  const float* bk = (const float*)d_in[4];
  const float* Wv = (const float*)d_in[5];
  const float* bv = (const float*)d_in[6];
  const float* Wd = (const float*)d_in[7];
  const float* bd = (const float*)d_in[8];

  char* w = (char*)d_ws;
  auto alloc = [&](size_t bytes) {
    char* p = w;
    w += (bytes + 255) & ~(size_t)255;
    return p;
  };
  short* xb = (short*)alloc((size_t)BB * SS * DD * 2);          // 8MB
  short* xT = (short*)alloc((size_t)BB * DD * SS * 2);          // 8MB
  short* WT = (short*)alloc((size_t)3 * HH * DD * 2);           // 1.5MB
  short* WdT = (short*)alloc((size_t)HH * SS * 2);              // 2MB
  float* bcat = (float*)alloc((size_t)3 * HH * 4);
  short* q = (short*)alloc((size_t)BB * SS * HH * 2);           // 8MB
  short* kT = (short*)alloc((size_t)BB * HH * SS * 2);          // 8MB
  short* vT = (short*)alloc((size_t)BB * HH * SS * 2);          // 8MB
  short* partM2 = (short*)alloc((size_t)BB * 4 * HH * HH * 2);  // 8MB
  short* partM3 = (short*)alloc((size_t)BB * 4 * HH * HH * 2);  // 8MB
  short* M2 = (short*)alloc((size_t)BB * HH * HH * 2);          // 2MB
  short* M3t = (short*)alloc((size_t)BB * DD * HH * 2);         // 2MB
  short* dense = (short*)alloc((size_t)BB * SS * HH * 2);       // 8MB

  dim3 tb(32, 8);
  prep<<<dim3(16, 64, 8), tb, 0, stream>>>(x, Wq, Wk, Wv, Wd, bq, bk, bv, xb,
                                           xT, WT, WdT, bcat);

  // Stage 1: q/kT/vT = x @ [Wq|Wk|Wv] + bias, direct layouts (768 blocks)
  gemm_qkv<<<dim3(BB * SS / 128, 12, 1), 256, 0, stream>>>(xb, WT, bcat, q, kT,
                                                           vT);
  // Stage 2a+3a split-K: partials for M2[b]=Wd^T@k[b], M3t[b]=x^T@v[b]
  // (1024 blocks)
  gemm_dual_split<<<dim3(8, 4, 32), 256, 0, stream>>>(WdT, kT, partM2, xT, vT,
                                                      partM3);
  reduce_part<<<dim3(128, 1, 8), 256, 0, stream>>>(partM2, partM3, M2, M3t);
  // Stage 2b: dense = sigmoid(q @ M2^T + bd)   [2048,512] K=512, batch 4
  gemm_bt<64, 2><<<dim3(SS / 64, HH / 128, BB), 256, 0, stream>>>(
      q, M2, dense, bd, HH, HH, HH, HH, (long)SS * HH, (long)HH * HH,
      (long)SS * HH);
  // Stage 3b: out = dense @ M3t^T   [2048,512] K=512, batch 4, f32 out
  gemm_bt<64, 3><<<dim3(SS / 64, DD / 128, BB), 256, 0, stream>>>(
      dense, M3t, d_out, nullptr, HH, HH, HH, DD, (long)SS * HH, (long)DD * HH,
      (long)SS * DD);
}

// Round 12
// 79.983 us; speedup vs baseline: 3.4019x; 1.0225x over previous
//
#include <hip/hip_runtime.h>
#include <hip/hip_bf16.h>
#include <stdint.h>

#define BB 4
#define SS 2048
#define DD 512
#define HH 512

typedef __attribute__((ext_vector_type(8))) short short8;
typedef __attribute__((ext_vector_type(4))) float floatx4;

typedef __attribute__((address_space(3))) uint32_t lds_u32_t;
typedef const __attribute__((address_space(1))) uint32_t glb_u32_t;

__device__ __forceinline__ void gload_lds16(const void* g, void* l) {
  __builtin_amdgcn_global_load_lds((glb_u32_t*)g, (lds_u32_t*)l, 16, 0, 0);
}

__device__ __forceinline__ short f2bf(float f) {
  __hip_bfloat16 h = __float2bfloat16(f);
  return __builtin_bit_cast(short, h);
}

__device__ __forceinline__ float bf2f(short s) {
  uint32_t u = ((uint32_t)(uint16_t)s) << 16;
  return __builtin_bit_cast(float, u);
}

// ---------------- GEMM main loop: acc += A-tile * B-tile^T ----------------
// A: [M,K] bf16 (lda), B: [N,K] bf16 (ldb). 512 threads = 8 waves in a 2x4
// grid (wave -> 64..BM/2 rows x 32 cols); BN=128, BK=64, single-buffered.
// LDS rows are 8 x 16B chunks; chunk c of row r holds global chunk c^(r&7)
// (source-side pre-swizzle; ds_read applies the same XOR).
// 8 waves/block doubles resident waves/CU vs the 4-wave version at the SAME
// LDS/tile/staging — more TLP to hide the per-iter vmcnt drain (m114).
template <int BM>
__device__ __forceinline__ void gemm_mainloop(const short* __restrict__ Ab,
                                              const short* __restrict__ Bb,
                                              int lda, int ldb, int K,
                                              floatx4 (&acc)[BM / 32][2]) {
  constexpr int BK = 64;
  constexpr int MF = BM / 32;  // 16-row frags per wave (wave owns BM/2 rows)
  __shared__ short As[BM * BK];
  __shared__ short Bs[128 * BK];

  const int t = threadIdx.x;
  const int lane = t & 63;
  const int wid = t >> 6;                  // 0..7
  const int wr = wid >> 2, wc = wid & 3;   // 2 x 4 wave grid
  const int r16 = lane & 15;
  const int hi = lane >> 4;  // 0..3

  const int srow = t >> 3;   // staging row within a 64-row slab (512 thr)
  const int schunk = t & 7;  // LDS 16B slot index within the row

#pragma unroll
  for (int i = 0; i < MF; i++)
#pragma unroll
    for (int j = 0; j < 2; j++) acc[i][j] = (floatx4)0.f;

  for (int k0 = 0; k0 < K; k0 += BK) {
#pragma unroll
    for (int s = 0; s < BM / 64; s++) {
      const int row = s * 64 + srow;
      const int g = schunk ^ (row & 7);  // global chunk for this LDS slot
      gload_lds16(Ab + (long)row * lda + k0 + g * 8,
                  &As[row * BK + schunk * 8]);
    }
#pragma unroll
    for (int s = 0; s < 2; s++) {
      const int row = s * 64 + srow;
      const int g = schunk ^ (row & 7);
      gload_lds16(Bb + (long)row * ldb + k0 + g * 8,
                  &Bs[row * BK + schunk * 8]);
    }
    __syncthreads();

    short8 af[MF][2], bfr[2][2];
#pragma unroll
    for (int i = 0; i < MF; i++) {
      const int row = wr * (BM / 2) + i * 16 + r16;
      const int x7 = row & 7;
      af[i][0] = *(const short8*)&As[row * BK + (hi ^ x7) * 8];
      af[i][1] = *(const short8*)&As[row * BK + ((hi + 4) ^ x7) * 8];
    }
#pragma unroll
    for (int j = 0; j < 2; j++) {
      const int row = wc * 32 + j * 16 + r16;
      const int x7 = row & 7;
      bfr[j][0] = *(const short8*)&Bs[row * BK + (hi ^ x7) * 8];
      bfr[j][1] = *(const short8*)&Bs[row * BK + ((hi + 4) ^ x7) * 8];
    }
#pragma unroll
    for (int i = 0; i < MF; i++)
#pragma unroll
      for (int j = 0; j < 2; j++) {
        acc[i][j] = __builtin_amdgcn_mfma_f32_16x16x32_bf16(
            af[i][0], bfr[j][0], acc[i][j], 0, 0, 0);
        acc[i][j] = __builtin_amdgcn_mfma_f32_16x16x32_bf16(
            af[i][1], bfr[j][1], acc[i][j], 0, 0, 0);
      }
    __syncthreads();
  }
}

// Standard row-major epilogue. C/D layout: col = lane&15, row = (lane>>4)*4+reg.
// EPI: 0 plain->bf16, 2 sigmoid(v+bias)->bf16, 3 plain->f32
template <int BM, int EPI>
__device__ __forceinline__ void epilogue_std(floatx4 (&acc)[BM / 32][2],
                                             void* __restrict__ Cm, long c_base,
                                             const float* __restrict__ bias,
                                             int ldc, long row0, long col0) {
  const int lane = threadIdx.x & 63;
  const int wid = threadIdx.x >> 6;
  const int wr = wid >> 2, wc = wid & 3;
  const int r16 = lane & 15;
#pragma unroll
  for (int i = 0; i < BM / 32; i++) {
    const long rbase = row0 + wr * (BM / 2) + i * 16 + (lane >> 4) * 4;
#pragma unroll
    for (int j = 0; j < 2; j++) {
      const long col = col0 + wc * 32 + j * 16 + r16;
      float bv = 0.f;
      if (EPI == 2) bv = bias[col];
#pragma unroll
      for (int rg = 0; rg < 4; rg++) {
        float v = acc[i][j][rg];
        if (EPI == 2) v = 1.f / (1.f + __expf(-(v + bv)));
        const long idx = c_base + (rbase + rg) * ldc + col;
        if (EPI == 3)
          ((float*)Cm)[idx] = v;
        else
          ((__hip_bfloat16*)Cm)[idx] = __float2bfloat16(v);
      }
    }
  }
}

template <int BM, int EPI>
__global__ __launch_bounds__(512) void gemm_bt(
    const short* __restrict__ A, const short* __restrict__ Bm,
    void* __restrict__ Cm, const float* __restrict__ bias, int K, int lda,
    int ldb, int ldc, long sA, long sB, long sC) {
  const int bz = blockIdx.z;
  floatx4 acc[BM / 32][2];
  const long row0 = (long)blockIdx.x * BM, col0 = (long)blockIdx.y * 128;
  gemm_mainloop<BM>(A + bz * sA + row0 * lda, Bm + bz * sB + col0 * ldb, lda,
                    ldb, K, acc);
  epilogue_std<BM, EPI>(acc, Cm, bz * sC, bias, ldc, row0, col0);
}

// Stage 1: qkv projection with direct-layout outputs. BM=128.
// y 0..3 -> q [b][S][H] row-major; y 4..7 -> kT [b][H][S]; y 8..11 -> vT.
__global__ __launch_bounds__(512) void gemm_qkv(
    const short* __restrict__ xb, const short* __restrict__ WT,
    const float* __restrict__ bcat, short* __restrict__ q,
    short* __restrict__ kT, short* __restrict__ vT) {
  floatx4 acc[4][2];
  const long row0 = (long)blockIdx.x * 128;  // global row over B*S
  const int y = blockIdx.y;
  gemm_mainloop<128>(xb + row0 * DD, WT + (long)y * 128 * DD, DD, DD, DD, acc);

  const int lane = threadIdx.x & 63;
  const int wid = threadIdx.x >> 6;
  const int wr = wid >> 2, wc = wid & 3;
  const int r16 = lane & 15;
  const int hi4 = (lane >> 4) * 4;
  const int mode = y >> 2;
  const int b = (int)(row0 >> 11);
  const int sblk = (int)(row0 & 2047);
  short* tp = (mode == 1) ? kT : vT;
#pragma unroll
  for (int i = 0; i < 4; i++) {
    const int s0 = sblk + wr * 64 + i * 16 + hi4;
#pragma unroll
    for (int j = 0; j < 2; j++) {
      const int colg = y * 128 + wc * 32 + j * 16 + r16;
      const float bv = bcat[colg];
      short o[4];
#pragma unroll
      for (int rg = 0; rg < 4; rg++) o[rg] = f2bf(acc[i][j][rg] + bv);
      if (mode == 0) {
#pragma unroll
        for (int rg = 0; rg < 4; rg++)
          q[((long)b * SS + s0 + rg) * HH + colg] = o[rg];
      } else {
        const int cl = colg - mode * 512;
        *(uint64_t*)&tp[((long)b * HH + cl) * SS + s0] = *(uint64_t*)o;
      }
    }
  }
}

// Split-K dual GEMM. BM=64. z = tb*4 + split; tb = task*4 + b.
// task 0: M2[b] = WdT @ kT[b]^T ; task 1: M3t[b] = xT[b] @ vT[b]^T
__global__ __launch_bounds__(512) void gemm_dual_split(
    const short* __restrict__ WdT, const short* __restrict__ kT,
    short* __restrict__ partM2, const short* __restrict__ xT,
    const short* __restrict__ vT, short* __restrict__ partM3) {
  const int bz = blockIdx.z;
  const int tb = bz >> 2, sp = bz & 3;
  const int task = tb >> 2, b = tb & 3;
  const short* A = (task ? xT + (long)b * HH * SS : WdT) + sp * 512;
  const short* B = (task ? vT : kT) + (long)b * HH * SS + sp * 512;
  short* C = (task ? partM3 : partM2) + ((long)(tb & 3) * 4 + sp) * HH * HH;
  floatx4 acc[2][2];
  const long row0 = (long)blockIdx.x * 64, col0 = (long)blockIdx.y * 128;
  gemm_mainloop<64>(A + row0 * SS, B + col0 * SS, SS, SS, 512, acc);
  epilogue_std<64, 0>(acc, C, 0, nullptr, HH, row0, col0);
}

// Sum 4 bf16 partials -> bf16. z = 0..7 (task*4+b), 8 elems/thread.
__global__ __launch_bounds__(256) void reduce_part(
    const short* __restrict__ partM2, const short* __restrict__ partM3,
    short* __restrict__ M2, short* __restrict__ M3t) {
  const int z = blockIdx.z;
  const int b = z & 3;
  const short* src = (z < 4 ? partM2 : partM3) + (long)b * 4 * HH * HH;
  short* dst = (z < 4 ? M2 : M3t) + (long)b * HH * HH;
  const long i = ((long)blockIdx.x * 256 + threadIdx.x) * 8;
  float s[8];
#pragma unroll
  for (int j = 0; j < 8; j++) s[j] = 0.f;
#pragma unroll
  for (int sp = 0; sp < 4; sp++) {
    short8 v = *(const short8*)&src[(long)sp * HH * HH + i];
#pragma unroll
    for (int j = 0; j < 8; j++) s[j] += bf2f(v[j]);
  }
  short o[8];
#pragma unroll
  for (int j = 0; j < 8; j++) o[j] = f2bf(s[j]);
  *(short8*)&dst[i] = *(short8*)o;
}

// ---------------- fused prep: x conversions + all weight prep ----------------
// grid (16, 64, 8), block (32,8).
// z 0..3: batch z of x: f32 [S][D] -> xb bf16 same layout AND xT bf16 [D][S]
// z 4..6: W{q,k,v} [512][512] -> WT[z-4] transposed bf16 (y<16)
//         z==4, y 16..21, x==0: bcat = [bq|bk|bv]
// z 7:    Wd [2048][512] -> WdT [512][2048] bf16
__global__ void prep(const float* __restrict__ x, const float* __restrict__ Wq,
                     const float* __restrict__ Wk, const float* __restrict__ Wv,
                     const float* __restrict__ Wd, const float* __restrict__ bq,
                     const float* __restrict__ bk, const float* __restrict__ bv,
                     short* __restrict__ xb, short* __restrict__ xT,
                     short* __restrict__ WT, short* __restrict__ WdT,
                     float* __restrict__ bcat) {
  __shared__ float tile[32][33];
  const int z = blockIdx.z, yb = blockIdx.y;
  const int tx = threadIdx.x, ty = threadIdx.y;
  if (z < 4) {
    const long b = z;
    const float* in = x + b * SS * DD;
    const int c0 = blockIdx.x * 32, r0 = yb * 32;  // c over D, r over S
#pragma unroll
    for (int i = 0; i < 32; i += 8) {
      float v = in[(long)(r0 + ty + i) * DD + c0 + tx];
      tile[ty + i][tx] = v;
      xb[(b * SS + r0 + ty + i) * DD + c0 + tx] = f2bf(v);
    }
    __syncthreads();
#pragma unroll
    for (int i = 0; i < 32; i += 8)
      xT[(b * DD + c0 + ty + i) * SS + r0 + tx] = f2bf(tile[tx][ty + i]);
  } else if (z < 7) {
    const int w = z - 4;
    if (yb < 16) {
      const float* in = w == 0 ? Wq : (w == 1 ? Wk : Wv);
      short* out = WT + (long)w * HH * DD;
      const int c0 = blockIdx.x * 32, r0 = yb * 32;
#pragma unroll
      for (int i = 0; i < 32; i += 8)
        tile[ty + i][tx] = in[(long)(r0 + ty + i) * HH + c0 + tx];
      __syncthreads();
#pragma unroll
      for (int i = 0; i < 32; i += 8)
        out[(long)(c0 + ty + i) * DD + r0 + tx] = f2bf(tile[tx][ty + i]);
    } else if (w == 0 && yb < 22 && blockIdx.x == 0) {
      const int i = (yb - 16) * 256 + ty * 32 + tx;
      bcat[i] = i < 512 ? bq[i] : (i < 1024 ? bk[i - 512] : bv[i - 1024]);
    }
  } else {
    const int c0 = blockIdx.x * 32, r0 = yb * 32;  // c over H, r over S
#pragma unroll
    for (int i = 0; i < 32; i += 8)
      tile[ty + i][tx] = Wd[(long)(r0 + ty + i) * HH + c0 + tx];
    __syncthreads();
#pragma unroll
    for (int i = 0; i < 32; i += 8)
      WdT[(long)(c0 + ty + i) * SS + r0 + tx] = f2bf(tile[tx][ty + i]);
  }
}

extern "C" void kernel_launch(void* const* d_in, const int* in_sizes, int n_in,
                              void* d_out, int out_size, void* d_ws,
                              size_t ws_size, hipStream_t stream) {
  (void)in_sizes;
  (void)n_in;
  (void)out_size;
  (void)ws_size;
  const float* x = (const float*)d_in[0];
  const float* Wq = (const float*)d_in[1];
  const float* bq = (const float*)d_in[2];
  const float* Wk = (const float*)d_in[3];
  const float* bk = (const float*)d_in[4];
  const float* Wv = (const float*)d_in[5];
  const float* bv = (const float*)d_in[6];
  const float* Wd = (const float*)d_in[7];
  const float* bd = (const float*)d_in[8];

  char* w = (char*)d_ws;
  auto alloc = [&](size_t bytes) {
    char* p = w;
    w += (bytes + 255) & ~(size_t)255;
    return p;
  };
  short* xb = (short*)alloc((size_t)BB * SS * DD * 2);          // 8MB
  short* xT = (short*)alloc((size_t)BB * DD * SS * 2);          // 8MB
  short* WT = (short*)alloc((size_t)3 * HH * DD * 2);           // 1.5MB
  short* WdT = (short*)alloc((size_t)HH * SS * 2);              // 2MB
  float* bcat = (float*)alloc((size_t)3 * HH * 4);
  short* q = (short*)alloc((size_t)BB * SS * HH * 2);           // 8MB
  short* kT = (short*)alloc((size_t)BB * HH * SS * 2);          // 8MB
  short* vT = (short*)alloc((size_t)BB * HH * SS * 2);          // 8MB
  short* partM2 = (short*)alloc((size_t)BB * 4 * HH * HH * 2);  // 8MB
  short* partM3 = (short*)alloc((size_t)BB * 4 * HH * HH * 2);  // 8MB
  short* M2 = (short*)alloc((size_t)BB * HH * HH * 2);          // 2MB
  short* M3t = (short*)alloc((size_t)BB * DD * HH * 2);         // 2MB
  short* dense = (short*)alloc((size_t)BB * SS * HH * 2);       // 8MB

  dim3 tb(32, 8);
  prep<<<dim3(16, 64, 8), tb, 0, stream>>>(x, Wq, Wk, Wv, Wd, bq, bk, bv, xb,
                                           xT, WT, WdT, bcat);

  // Stage 1: q/kT/vT = x @ [Wq|Wk|Wv] + bias, direct layouts (768 blocks)
  gemm_qkv<<<dim3(BB * SS / 128, 12, 1), 512, 0, stream>>>(xb, WT, bcat, q, kT,
                                                           vT);
  // Stage 2a+3a split-K: partials for M2[b]=Wd^T@k[b], M3t[b]=x^T@v[b]
  // (1024 blocks)
  gemm_dual_split<<<dim3(8, 4, 32), 512, 0, stream>>>(WdT, kT, partM2, xT, vT,
                                                      partM3);
  reduce_part<<<dim3(128, 1, 8), 256, 0, stream>>>(partM2, partM3, M2, M3t);
  // Stage 2b: dense = sigmoid(q @ M2^T + bd)   [2048,512] K=512, batch 4
  gemm_bt<64, 2><<<dim3(SS / 64, HH / 128, BB), 512, 0, stream>>>(
      q, M2, dense, bd, HH, HH, HH, HH, (long)SS * HH, (long)HH * HH,
      (long)SS * HH);
  // Stage 3b: out = dense @ M3t^T   [2048,512] K=512, batch 4, f32 out
  gemm_bt<64, 3><<<dim3(SS / 64, DD / 128, BB), 512, 0, stream>>>(
      dense, M3t, d_out, nullptr, HH, HH, HH, DD, (long)SS * HH, (long)DD * HH,
      (long)SS * DD);
}